// Round 6
// baseline (693.764 us; speedup 1.0000x reference)
//
#include <hip/hip_runtime.h>
#include <stdint.h>

typedef unsigned short u16;
typedef short s16x8 __attribute__((ext_vector_type(8)));
typedef unsigned short u16x8 __attribute__((ext_vector_type(8)));
typedef float f32x4 __attribute__((ext_vector_type(4)));

#define S_LEN 2048
#define NBATCH 2
#define HID 3584
#define NH 28
#define NKV 4
#define HD 128
#define QSZ 3584
#define KVSZ 512
#define QKV_N 4608
#define RSCALE 0.08838834764831845f  // 128^-0.5

__device__ __forceinline__ u16 f2bf(float f) {
    union { float f; uint32_t u; } x; x.f = f;
    uint32_t r = x.u + 0x7FFF + ((x.u >> 16) & 1);
    return (u16)(r >> 16);
}
__device__ __forceinline__ float bf2f(u16 u) {
    union { uint32_t u; float f; } x; x.u = ((uint32_t)u) << 16;
    return x.f;
}
__device__ __forceinline__ void async_load16(const u16* g, u16* l) {
    __builtin_amdgcn_global_load_lds((const __attribute__((address_space(1))) void*)g,
                                     (__attribute__((address_space(3))) void*)l, 16, 0, 0);
}

// ---------------- fp32 -> bf16 convert ----------------
__global__ __launch_bounds__(256) void cvt_bf16_kernel(const float* __restrict__ in,
                                                       u16* __restrict__ out, int n4) {
    int i = blockIdx.x * 256 + threadIdx.x;
    if (i >= n4) return;
    float4 v = ((const float4*)in)[i];
    ushort4 o;
    o.x = f2bf(v.x); o.y = f2bf(v.y); o.z = f2bf(v.z); o.w = f2bf(v.w);
    ((ushort4*)out)[i] = o;
}

// ---------------- transpose + convert: out[c][r] = bf16(in[r][c]) ----------------
__global__ __launch_bounds__(256) void transpose_cvt_kernel(const float* __restrict__ in,
                                                            u16* __restrict__ out, int R, int C) {
    __shared__ float tile[32][33];
    int r0 = blockIdx.y * 32, c0 = blockIdx.x * 32;
    int t = threadIdx.x;
    int tr = t >> 3, tc = (t & 7) * 4;
    float4 v = *(const float4*)&in[(size_t)(r0 + tr) * C + c0 + tc];
    tile[tr][tc + 0] = v.x; tile[tr][tc + 1] = v.y;
    tile[tr][tc + 2] = v.z; tile[tr][tc + 3] = v.w;
    __syncthreads();
    ushort4 o;
    o.x = f2bf(tile[tc + 0][tr]);
    o.y = f2bf(tile[tc + 1][tr]);
    o.z = f2bf(tile[tc + 2][tr]);
    o.w = f2bf(tile[tc + 3][tr]);
    *(ushort4*)&out[(size_t)(c0 + tr) * R + r0 + tc] = o;
}

// ---------------- 128x128 4-wave MFMA GEMM + XCD-aware tile swizzle ----------
template <bool BIAS, bool OUTBF16>
__global__ __launch_bounds__(256) void gemm_kernel(const u16* __restrict__ A,
                                                   const u16* __restrict__ Bt,
                                                   const float* __restrict__ bias,
                                                   void* __restrict__ Cout,
                                                   int M, int N, int K) {
    __shared__ __align__(16) u16 As[128 * 64];
    __shared__ __align__(16) u16 Bs[128 * 64];
    int t = threadIdx.x;
    int w = t >> 6, l = t & 63;
    int lane16 = l & 15, quad = l >> 4;
    // T1: XCD-aware bijective swizzle (requires nwg % 8 == 0; 1152 for QKV).
    // Each XCD gets a contiguous row-major chunk of tile space -> A-panel L2 reuse.
    int nwg = gridDim.x * gridDim.y;
    int wgid = blockIdx.y * gridDim.x + blockIdx.x;
    int swz = (wgid & 7) * (nwg >> 3) + (wgid >> 3);
    int m0 = (swz / gridDim.x) * 128, n0 = (swz % gridDim.x) * 128;
    int wm = (w >> 1) * 64, wn = (w & 1) * 64;

    f32x4 z = {0.f, 0.f, 0.f, 0.f};
    f32x4 acc[4][4];
#pragma unroll
    for (int i = 0; i < 4; ++i)
#pragma unroll
        for (int j = 0; j < 4; ++j) acc[i][j] = z;

    int srow = l >> 3;
    int scol = l & 7;
    int nk = K >> 6;
    for (int kt = 0; kt < nk; ++kt) {
#pragma unroll
        for (int j = 0; j < 4; ++j) {
            int seg = w * 4 + j;
            int row = seg * 8 + srow;
            int cg = scol ^ (row & 7);
            async_load16(A + (size_t)(m0 + row) * K + kt * 64 + cg * 8, As + seg * 512);
        }
#pragma unroll
        for (int j = 0; j < 4; ++j) {
            int seg = w * 4 + j;
            int row = seg * 8 + srow;
            int cg = scol ^ (row & 7);
            async_load16(Bt + (size_t)(n0 + row) * K + kt * 64 + cg * 8, Bs + seg * 512);
        }
        __syncthreads();
#pragma unroll
        for (int ks = 0; ks < 2; ++ks) {
            s16x8 af[4], bf[4];
#pragma unroll
            for (int mi = 0; mi < 4; ++mi) {
                int r = wm + mi * 16 + lane16;
                int ch = (ks * 4 + quad) ^ (r & 7);
                af[mi] = *(const s16x8*)&As[r * 64 + ch * 8];
            }
#pragma unroll
            for (int ni = 0; ni < 4; ++ni) {
                int r = wn + ni * 16 + lane16;
                int ch = (ks * 4 + quad) ^ (r & 7);
                bf[ni] = *(const s16x8*)&Bs[r * 64 + ch * 8];
            }
#pragma unroll
            for (int mi = 0; mi < 4; ++mi)
#pragma unroll
                for (int ni = 0; ni < 4; ++ni)
                    acc[mi][ni] = __builtin_amdgcn_mfma_f32_16x16x32_bf16(af[mi], bf[ni], acc[mi][ni], 0, 0, 0);
        }
        __syncthreads();
    }
#pragma unroll
    for (int ni = 0; ni < 4; ++ni) {
        int col = n0 + wn + ni * 16 + lane16;
        float bv = BIAS ? bias[col] : 0.0f;
#pragma unroll
        for (int mi = 0; mi < 4; ++mi) {
#pragma unroll
            for (int r = 0; r < 4; ++r) {
                int rowg = m0 + wm + mi * 16 + quad * 4 + r;
                float v = acc[mi][ni][r] + bv;
                if (OUTBF16)
                    ((u16*)Cout)[(size_t)rowg * N + col] = f2bf(v);
                else
                    ((float*)Cout)[(size_t)rowg * N + col] = v;
            }
        }
    }
}

// ---------------- 256x256 8-wave double-buffered counted-vmcnt MFMA GEMM -------------
// Use ONLY when grid <= 256 blocks (single scheduling round). + XCD swizzle (nwg%8==0).
template <bool BIAS, bool OUTBF16>
__global__ __launch_bounds__(512, 2) void gemm256_kernel(const u16* __restrict__ A,
                                                         const u16* __restrict__ Bt,
                                                         const float* __restrict__ bias,
                                                         void* __restrict__ Cout,
                                                         int M, int N, int K) {
    __shared__ __align__(16) u16 As[2 * 256 * 64];
    __shared__ __align__(16) u16 Bs[2 * 256 * 64];
    int t = threadIdx.x;
    int w = t >> 6, l = t & 63;
    int lane16 = l & 15, quad = l >> 4;
    int nwg = gridDim.x * gridDim.y;
    int wgid = blockIdx.y * gridDim.x + blockIdx.x;
    int swz = (wgid & 7) * (nwg >> 3) + (wgid >> 3);
    int m0 = (swz / gridDim.x) * 256, n0 = (swz % gridDim.x) * 256;
    int wm2 = w >> 2, wn4 = w & 3;   // 2 x 4 wave grid

    f32x4 z = {0.f, 0.f, 0.f, 0.f};
    f32x4 acc[8][4];
#pragma unroll
    for (int i = 0; i < 8; ++i)
#pragma unroll
        for (int j = 0; j < 4; ++j) acc[i][j] = z;

    auto STAGE = [&](int p, int kt) {
        const u16* ak = A + kt * 64;
        const u16* bk = Bt + kt * 64;
#pragma unroll
        for (int j = 0; j < 4; ++j) {
            int idx = j * 512 + t;
            int row = idx >> 3;
            int cg = (idx & 7) ^ (row & 7);
            async_load16(ak + (size_t)(m0 + row) * K + cg * 8,
                         As + p * 16384 + j * 4096 + w * 512);
        }
#pragma unroll
        for (int j = 0; j < 4; ++j) {
            int idx = j * 512 + t;
            int row = idx >> 3;
            int cg = (idx & 7) ^ (row & 7);
            async_load16(bk + (size_t)(n0 + row) * K + cg * 8,
                         Bs + p * 16384 + j * 4096 + w * 512);
        }
    };

    auto COMPUTE = [&](int p) {
        const u16* Asp = As + p * 16384;
        const u16* Bsp = Bs + p * 16384;
#pragma unroll
        for (int mh = 0; mh < 2; ++mh) {
            s16x8 af[4][2];
#pragma unroll
            for (int mi = 0; mi < 4; ++mi) {
                int r = wm2 * 128 + mh * 64 + mi * 16 + lane16;
#pragma unroll
                for (int ks = 0; ks < 2; ++ks) {
                    int ch = (ks * 4 + quad) ^ (r & 7);
                    af[mi][ks] = *(const s16x8*)&Asp[r * 64 + ch * 8];
                }
            }
#pragma unroll
            for (int nh = 0; nh < 2; ++nh) {
                s16x8 bfr[2][2];
#pragma unroll
                for (int ni = 0; ni < 2; ++ni) {
                    int r = wn4 * 64 + nh * 32 + ni * 16 + lane16;
#pragma unroll
                    for (int ks = 0; ks < 2; ++ks) {
                        int ch = (ks * 4 + quad) ^ (r & 7);
                        bfr[ni][ks] = *(const s16x8*)&Bsp[r * 64 + ch * 8];
                    }
                }
                __builtin_amdgcn_s_setprio(1);
#pragma unroll
                for (int ks = 0; ks < 2; ++ks)
#pragma unroll
                    for (int mi = 0; mi < 4; ++mi)
#pragma unroll
                        for (int ni = 0; ni < 2; ++ni)
                            acc[mh * 4 + mi][nh * 2 + ni] = __builtin_amdgcn_mfma_f32_16x16x32_bf16(
                                af[mi][ks], bfr[ni][ks], acc[mh * 4 + mi][nh * 2 + ni], 0, 0, 0);
                __builtin_amdgcn_s_setprio(0);
            }
        }
    };

    int nk = K >> 6;
    STAGE(0, 0);
#pragma unroll 1
    for (int kt = 0; kt < nk; ++kt) {
        int p = kt & 1;
        if (kt + 1 < nk) {
            STAGE(p ^ 1, kt + 1);                              // next tile in flight
            asm volatile("s_waitcnt vmcnt(8)" ::: "memory");   // tile kt done; kt+1 stays in flight
        } else {
            asm volatile("s_waitcnt vmcnt(0)" ::: "memory");
        }
        __builtin_amdgcn_s_barrier();          // all waves' tile-kt loads landed
        __builtin_amdgcn_sched_barrier(0);     // no ds_read hoists above the barrier
        COMPUTE(p);
        asm volatile("s_waitcnt lgkmcnt(0)" ::: "memory");
        __builtin_amdgcn_s_barrier();          // all waves done reading buf p
    }

#pragma unroll
    for (int nj = 0; nj < 4; ++nj) {
        int col = n0 + wn4 * 64 + nj * 16 + lane16;
        float bv = BIAS ? bias[col] : 0.0f;
#pragma unroll
        for (int mj = 0; mj < 8; ++mj) {
#pragma unroll
            for (int r = 0; r < 4; ++r) {
                int rowg = m0 + wm2 * 128 + mj * 16 + quad * 4 + r;
                float v = acc[mj][nj][r] + bv;
                if (OUTBF16)
                    ((u16*)Cout)[(size_t)rowg * N + col] = f2bf(v);
                else
                    ((float*)Cout)[(size_t)rowg * N + col] = v;
            }
        }
    }
}

// ---------------- RoPE for K only (Q-RoPE fused into attn) ----------------
__global__ __launch_bounds__(256) void ropek_kernel(const u16* __restrict__ qkv,
                                                    const int* __restrict__ positions,
                                                    u16* __restrict__ Kout) {
    int row = blockIdx.x;           // b*S + s
    int b = row >> 11, s = row & 2047;
    int t = threadIdx.x;
    int i = t & 63;
    int g = t >> 6;
    float pos = (float)positions[row];
    float freq = exp2f((float)(2 * i) * (-13.287712379549449f / 128.0f));
    float ang = pos * freq;
    float sn, cs;
    sincosf(ang, &sn, &cs);
    const u16* qrow = qkv + (size_t)row * QKV_N;
    float x1 = bf2f(qrow[QSZ + g * HD + i]);
    float x2 = bf2f(qrow[QSZ + g * HD + 64 + i]);
    u16* ko = Kout + ((size_t)(b * NKV + g) * S_LEN + s) * HD;
    ko[i]      = f2bf(x1 * cs - x2 * sn);
    ko[64 + i] = f2bf(x2 * cs + x1 * sn);
}

// ---------------- V transpose: qkv[:, QSZ+KVSZ:] -> Vt[b][c][s] (u16, LDS-tiled) ----------------
__global__ __launch_bounds__(256) void vtrans_kernel(const u16* __restrict__ qkv,
                                                     u16* __restrict__ Vt) {
    __shared__ u16 T[64 * 72];
    int t = threadIdx.x;
    int c0 = blockIdx.x * 64, s0 = blockIdx.y * 64, b = blockIdx.z;
    const u16* src = qkv + (size_t)b * 2048 * QKV_N + QSZ + KVSZ + c0;
#pragma unroll
    for (int i = 0; i < 2; ++i) {
        int idx = i * 256 + t;
        int sr = idx >> 3, ch = idx & 7;
        u16x8 v = *(const u16x8*)&src[(size_t)(s0 + sr) * QKV_N + ch * 8];
#pragma unroll
        for (int j = 0; j < 8; ++j) T[(ch * 8 + j) * 72 + sr] = v[j];
    }
    __syncthreads();
    u16* dst = Vt + (size_t)b * 512 * 2048;
#pragma unroll
    for (int i = 0; i < 2; ++i) {
        int idx = i * 256 + t;
        int cr = idx >> 3, ch = idx & 7;
        *(u16x8*)&dst[(size_t)(c0 + cr) * 2048 + s0 + ch * 8] = *(const u16x8*)&T[cr * 72 + ch * 8];
    }
}

// ---------------- flash attention (causal, GQA-fused, Q-RoPE fused) ----------------
// KVBLK = 128 (was 64): halves per-iteration fixed costs (2 barriers, staging chain,
// QK->softmax->PV serialization) which round-5's null DS-op reduction identified as
// the real bottleneck. 17 uniform K-iterations per block (p and 63-p pairing).
// LDS: Ks 32KB + Vs 32KB + Ps 7x32x136x2B = 60.9KB -> 126.5KB, 1 block/CU (grid=256).
__global__ __launch_bounds__(512, 2) void attn_kernel(const u16* __restrict__ qkv,
                                                      const int* __restrict__ positions,
                                                      const u16* __restrict__ K,
                                                      const u16* __restrict__ Vt,
                                                      u16* __restrict__ O) {
    __shared__ __align__(16) u16 Ks[128 * 128];
    __shared__ __align__(16) u16 Vs[128 * 128];
    __shared__ __align__(16) u16 Ps[7 * 32 * 136];
    int p = blockIdx.x;             // 0..31  (q-tile pair)
    int bh = blockIdx.y;            // b*4 + hk
    int b = bh >> 2, hk = bh & 3;
    int t = threadIdx.x, w = t >> 6, l = t & 63;
    int lane16 = l & 15, quad = l >> 4;
    const u16* Kb = K + (size_t)(b * NKV + hk) * S_LEN * HD;
    const u16* Vb = Vt + (size_t)(b * NKV + hk) * HD * S_LEN;
    int wc = (w < 7) ? w : 6;       // clamp so wave 7's pointer math stays in-bounds
    int h = hk * 7 + wc;
    u16* Pw = Ps + wc * (32 * 136);

    u16x8 kr[4], vr_[4];
    auto stageR = [&](int kt) {
#pragma unroll
        for (int j = 0; j < 4; ++j) {
            int idx = j * 512 + t;
            kr[j] = *(const u16x8*)&Kb[(size_t)(kt * 128 + (idx >> 4)) * HD + (idx & 15) * 8];
        }
#pragma unroll
        for (int j = 0; j < 4; ++j) {
            int idx = j * 512 + t;
            vr_[j] = *(const u16x8*)&Vb[(size_t)(idx >> 4) * S_LEN + kt * 128 + (idx & 15) * 8];
        }
    };
    auto dsw = [&]() {
#pragma unroll
        for (int j = 0; j < 4; ++j) {
            int idx = j * 512 + t;
            int row = idx >> 4, c = idx & 15;
            *(u16x8*)&Ks[row * 128 + ((c ^ (row & 15))) * 8] = kr[j];
        }
#pragma unroll
        for (int j = 0; j < 4; ++j) {
            int idx = j * 512 + t;
            int row = idx >> 4, c = idx & 15;
            *(u16x8*)&Vs[row * 128 + ((c ^ (row & 7))) * 8] = vr_[j];
        }
    };

    f32x4 z = {0.f, 0.f, 0.f, 0.f};

#pragma unroll 1
    for (int phase = 0; phase < 2; ++phase) {
        int q0 = (phase == 0) ? p * 32 : (63 - p) * 32;
        int nkt = (q0 >> 7) + 1;

        // Q load from qkv + in-register neox RoPE (pairs d, d+64 live in kd and kd+2)
        s16x8 qf[2][4];
        if (w < 7) {
#pragma unroll
            for (int st = 0; st < 2; ++st) {
                int qrow = q0 + st * 16 + lane16;
                const u16* qsrc = qkv + (size_t)(b * S_LEN + qrow) * QKV_N + h * HD;
                u16x8 raw[4];
#pragma unroll
                for (int kd = 0; kd < 4; ++kd)
                    raw[kd] = *(const u16x8*)(qsrc + kd * 32 + quad * 8);
                float pos = (float)positions[b * S_LEN + qrow];
#pragma unroll
                for (int kd = 0; kd < 2; ++kd) {
                    s16x8 lo, hi;
#pragma unroll
                    for (int j = 0; j < 8; ++j) {
                        int d = kd * 32 + quad * 8 + j;
                        float fr = exp2f((float)(2 * d) * (-13.287712379549449f / 128.0f));
                        float sn, cs;
                        sincosf(pos * fr, &sn, &cs);
                        float x1 = bf2f(raw[kd][j]);
                        float x2 = bf2f(raw[kd + 2][j]);
                        lo[j] = (short)f2bf((x1 * cs - x2 * sn) * RSCALE);
                        hi[j] = (short)f2bf((x2 * cs + x1 * sn) * RSCALE);
                    }
                    qf[st][kd] = lo;
                    qf[st][kd + 2] = hi;
                }
            }
        }
        f32x4 oacc[2][8];
        float m_r[2][4], l_r[2][4];
#pragma unroll
        for (int st = 0; st < 2; ++st) {
#pragma unroll
            for (int i = 0; i < 8; ++i) oacc[st][i] = z;
#pragma unroll
            for (int r = 0; r < 4; ++r) { m_r[st][r] = -3.0e38f; l_r[st][r] = 0.f; }
        }

        stageR(0);
#pragma unroll 1
        for (int kt = 0; kt < nkt; ++kt) {
            __syncthreads();                 // all waves done reading previous tile
            dsw();                           // LDS <- regs (tile kt)
            __syncthreads();
            if (kt + 1 < nkt) stageR(kt + 1);  // issue next tile's global loads now
            if (w < 7) {
                // per-st: QK^T + softmax + P staging (sa[8] keeps VGPR under control)
#pragma unroll
                for (int st = 0; st < 2; ++st) {
                    f32x4 sa[8];
#pragma unroll
                    for (int ni = 0; ni < 8; ++ni) sa[ni] = z;
                    __builtin_amdgcn_s_setprio(1);
#pragma unroll
                    for (int kd = 0; kd < 4; ++kd) {
#pragma unroll
                        for (int ni = 0; ni < 8; ++ni) {
                            int srow = ni * 16 + lane16;
                            int ch = (kd * 4 + quad) ^ lane16;
                            s16x8 kf = *(const s16x8*)&Ks[srow * 128 + ch * 8];
                            sa[ni] = __builtin_amdgcn_mfma_f32_16x16x32_bf16(qf[st][kd], kf, sa[ni], 0, 0, 0);
                        }
                    }
                    __builtin_amdgcn_s_setprio(0);
                    if (kt == nkt - 1) {
#pragma unroll
                        for (int ni = 0; ni < 8; ++ni)
#pragma unroll
                            for (int r = 0; r < 4; ++r) {
                                int colg = kt * 128 + ni * 16 + lane16;
                                int rowg = q0 + st * 16 + quad * 4 + r;
                                if (colg > rowg) sa[ni][r] = -3.0e38f;
                            }
                    }
                    float mx[4];
#pragma unroll
                    for (int r = 0; r < 4; ++r) {
                        float a0 = fmaxf(fmaxf(sa[0][r], sa[1][r]), fmaxf(sa[2][r], sa[3][r]));
                        float a1 = fmaxf(fmaxf(sa[4][r], sa[5][r]), fmaxf(sa[6][r], sa[7][r]));
                        mx[r] = fmaxf(a0, a1);
                        mx[r] = fmaxf(mx[r], __shfl_xor(mx[r], 1));
                        mx[r] = fmaxf(mx[r], __shfl_xor(mx[r], 2));
                        mx[r] = fmaxf(mx[r], __shfl_xor(mx[r], 4));
                        mx[r] = fmaxf(mx[r], __shfl_xor(mx[r], 8));
                    }
                    float al[4], rs[4], pp[8][4];
#pragma unroll
                    for (int r = 0; r < 4; ++r) {
                        float mn = fmaxf(m_r[st][r], mx[r]);
                        al[r] = __expf(m_r[st][r] - mn);
                        m_r[st][r] = mn;
                        rs[r] = 0.f;
                    }
#pragma unroll
                    for (int ni = 0; ni < 8; ++ni)
#pragma unroll
                        for (int r = 0; r < 4; ++r) {
                            pp[ni][r] = __expf(sa[ni][r] - m_r[st][r]);
                            rs[r] += pp[ni][r];
                        }
#pragma unroll
                    for (int r = 0; r < 4; ++r) {
                        rs[r] += __shfl_xor(rs[r], 1);
                        rs[r] += __shfl_xor(rs[r], 2);
                        rs[r] += __shfl_xor(rs[r], 4);
                        rs[r] += __shfl_xor(rs[r], 8);
                        l_r[st][r] = l_r[st][r] * al[r] + rs[r];
                    }
#pragma unroll
                    for (int i = 0; i < 8; ++i)
#pragma unroll
                        for (int r = 0; r < 4; ++r) oacc[st][i][r] *= al[r];
#pragma unroll
                    for (int ni = 0; ni < 8; ++ni)
#pragma unroll
                        for (int r = 0; r < 4; ++r)
                            Pw[(st * 16 + quad * 4 + r) * 136 + ni * 16 + lane16] = f2bf(pp[ni][r]);
                }
                // PV: V fragment read ONCE, used by both st
                __builtin_amdgcn_s_setprio(1);
#pragma unroll
                for (int ks = 0; ks < 4; ++ks) {
                    s16x8 pf0 = *(const s16x8*)&Pw[(lane16) * 136 + ks * 32 + quad * 8];
                    s16x8 pf1 = *(const s16x8*)&Pw[(16 + lane16) * 136 + ks * 32 + quad * 8];
#pragma unroll
                    for (int ni2 = 0; ni2 < 8; ++ni2) {
                        int vr = ni2 * 16 + lane16;
                        int ch = (ks * 4 + quad) ^ (vr & 7);
                        s16x8 vf = *(const s16x8*)&Vs[vr * 128 + ch * 8];
                        oacc[0][ni2] = __builtin_amdgcn_mfma_f32_16x16x32_bf16(pf0, vf, oacc[0][ni2], 0, 0, 0);
                        oacc[1][ni2] = __builtin_amdgcn_mfma_f32_16x16x32_bf16(pf1, vf, oacc[1][ni2], 0, 0, 0);
                    }
                }
                __builtin_amdgcn_s_setprio(0);
            }
        }
        // epilogue for this q-tile
        if (w < 7) {
#pragma unroll
            for (int st = 0; st < 2; ++st) {
                float inv[4];
#pragma unroll
                for (int r = 0; r < 4; ++r) inv[r] = 1.0f / l_r[st][r];
#pragma unroll
                for (int ni2 = 0; ni2 < 8; ++ni2)
#pragma unroll
                    for (int r = 0; r < 4; ++r) {
                        int rowg = q0 + st * 16 + quad * 4 + r;
                        int colg = h * HD + ni2 * 16 + lane16;
                        O[((size_t)b * S_LEN + rowg) * QSZ + colg] = f2bf(oacc[st][ni2][r] * inv[r]);
                    }
            }
        }
    }
}

extern "C" void kernel_launch(void* const* d_in, const int* in_sizes, int n_in,
                              void* d_out, int out_size, void* d_ws, size_t ws_size,
                              hipStream_t stream) {
    const int* positions = (const int*)d_in[0];
    const float* hs = (const float*)d_in[1];
    const float* Wqkv = (const float*)d_in[2];
    const float* bqkv = (const float*)d_in[3];
    const float* Wo = (const float*)d_in[4];
    float* out = (float*)d_out;
    char* ws = (char*)d_ws;

    u16* hsb   = (u16*)(ws + 0);          // GEMM input; reused as attn OUTPUT after QKV
    u16* Wqkvt = (u16*)(ws + 29360128);
    u16* Wot   = (u16*)(ws + 62390272);
    u16* qkv   = (u16*)(ws + 88080384);   // stays live through attn (Q read in-place)
    u16* Kbuf  = (u16*)(ws + 125829120);
    u16* Vtb   = (u16*)(ws + 130023424);
    u16* attn  = hsb;                     // 2*2048*3584*2B = 29360128B, exact fit

    hipLaunchKernelGGL(cvt_bf16_kernel, dim3(14336), dim3(256), 0, stream, hs, hsb, 3670016);
    hipLaunchKernelGGL(transpose_cvt_kernel, dim3(144, 112), dim3(256), 0, stream, Wqkv, Wqkvt, 3584, 4608);
    hipLaunchKernelGGL(transpose_cvt_kernel, dim3(112, 112), dim3(256), 0, stream, Wo, Wot, 3584, 3584);
    // QKV: 1152 small 128^2 blocks pack tail-free; nwg%8==0 so XCD swizzle is bijective.
    hipLaunchKernelGGL((gemm_kernel<true, true>), dim3(36, 32), dim3(256), 0, stream,
                       hsb, Wqkvt, bqkv, (void*)qkv, 4096, 4608, 3584);
    hipLaunchKernelGGL(ropek_kernel, dim3(4096), dim3(256), 0, stream, qkv, positions, Kbuf);
    hipLaunchKernelGGL(vtrans_kernel, dim3(8, 32, 2), dim3(256), 0, stream, qkv, Vtb);
    hipLaunchKernelGGL(attn_kernel, dim3(32, 8), dim3(512), 0, stream, qkv, positions, Kbuf, Vtb, attn);
    // Out-proj: 224 tiles < 256 CUs -> single round; nwg%8==0 swizzle.
    hipLaunchKernelGGL((gemm256_kernel<false, false>), dim3(14, 16), dim3(512), 0, stream,
                       attn, Wot, (const float*)nullptr, (void*)out, 4096, 3584, 3584);
}

// Round 7
// 648.766 us; speedup vs baseline: 1.0694x; 1.0694x over previous
//
#include <hip/hip_runtime.h>
#include <stdint.h>

typedef unsigned short u16;
typedef short s16x8 __attribute__((ext_vector_type(8)));
typedef unsigned short u16x8 __attribute__((ext_vector_type(8)));
typedef float f32x4 __attribute__((ext_vector_type(4)));

#define S_LEN 2048
#define NBATCH 2
#define HID 3584
#define NH 28
#define NKV 4
#define HD 128
#define QSZ 3584
#define KVSZ 512
#define QKV_N 4608
#define RSCALE 0.08838834764831845f  // 128^-0.5

__device__ __forceinline__ u16 f2bf(float f) {
    union { float f; uint32_t u; } x; x.f = f;
    uint32_t r = x.u + 0x7FFF + ((x.u >> 16) & 1);
    return (u16)(r >> 16);
}
__device__ __forceinline__ float bf2f(u16 u) {
    union { uint32_t u; float f; } x; x.u = ((uint32_t)u) << 16;
    return x.f;
}
__device__ __forceinline__ void async_load16(const u16* g, u16* l) {
    __builtin_amdgcn_global_load_lds((const __attribute__((address_space(1))) void*)g,
                                     (__attribute__((address_space(3))) void*)l, 16, 0, 0);
}

// ---------------- fp32 -> bf16 convert ----------------
__global__ __launch_bounds__(256) void cvt_bf16_kernel(const float* __restrict__ in,
                                                       u16* __restrict__ out, int n4) {
    int i = blockIdx.x * 256 + threadIdx.x;
    if (i >= n4) return;
    float4 v = ((const float4*)in)[i];
    ushort4 o;
    o.x = f2bf(v.x); o.y = f2bf(v.y); o.z = f2bf(v.z); o.w = f2bf(v.w);
    ((ushort4*)out)[i] = o;
}

// ---------------- transpose + convert: out[c][r] = bf16(in[r][c]) ----------------
__global__ __launch_bounds__(256) void transpose_cvt_kernel(const float* __restrict__ in,
                                                            u16* __restrict__ out, int R, int C) {
    __shared__ float tile[32][33];
    int r0 = blockIdx.y * 32, c0 = blockIdx.x * 32;
    int t = threadIdx.x;
    int tr = t >> 3, tc = (t & 7) * 4;
    float4 v = *(const float4*)&in[(size_t)(r0 + tr) * C + c0 + tc];
    tile[tr][tc + 0] = v.x; tile[tr][tc + 1] = v.y;
    tile[tr][tc + 2] = v.z; tile[tr][tc + 3] = v.w;
    __syncthreads();
    ushort4 o;
    o.x = f2bf(tile[tc + 0][tr]);
    o.y = f2bf(tile[tc + 1][tr]);
    o.z = f2bf(tile[tc + 2][tr]);
    o.w = f2bf(tile[tc + 3][tr]);
    *(ushort4*)&out[(size_t)(c0 + tr) * R + r0 + tc] = o;
}

// ---------------- 128x128 4-wave MFMA GEMM (no swizzle — round-6 showed swizzle
// chunking forces whole-B per XCD L2, FETCH +59%) ----------
template <bool BIAS, bool OUTBF16>
__global__ __launch_bounds__(256) void gemm_kernel(const u16* __restrict__ A,
                                                   const u16* __restrict__ Bt,
                                                   const float* __restrict__ bias,
                                                   void* __restrict__ Cout,
                                                   int M, int N, int K) {
    __shared__ __align__(16) u16 As[128 * 64];
    __shared__ __align__(16) u16 Bs[128 * 64];
    int t = threadIdx.x;
    int w = t >> 6, l = t & 63;
    int lane16 = l & 15, quad = l >> 4;
    int m0 = blockIdx.y * 128, n0 = blockIdx.x * 128;
    int wm = (w >> 1) * 64, wn = (w & 1) * 64;

    f32x4 z = {0.f, 0.f, 0.f, 0.f};
    f32x4 acc[4][4];
#pragma unroll
    for (int i = 0; i < 4; ++i)
#pragma unroll
        for (int j = 0; j < 4; ++j) acc[i][j] = z;

    int srow = l >> 3;
    int scol = l & 7;
    int nk = K >> 6;
    for (int kt = 0; kt < nk; ++kt) {
#pragma unroll
        for (int j = 0; j < 4; ++j) {
            int seg = w * 4 + j;
            int row = seg * 8 + srow;
            int cg = scol ^ (row & 7);
            async_load16(A + (size_t)(m0 + row) * K + kt * 64 + cg * 8, As + seg * 512);
        }
#pragma unroll
        for (int j = 0; j < 4; ++j) {
            int seg = w * 4 + j;
            int row = seg * 8 + srow;
            int cg = scol ^ (row & 7);
            async_load16(Bt + (size_t)(n0 + row) * K + kt * 64 + cg * 8, Bs + seg * 512);
        }
        __syncthreads();
#pragma unroll
        for (int ks = 0; ks < 2; ++ks) {
            s16x8 af[4], bf[4];
#pragma unroll
            for (int mi = 0; mi < 4; ++mi) {
                int r = wm + mi * 16 + lane16;
                int ch = (ks * 4 + quad) ^ (r & 7);
                af[mi] = *(const s16x8*)&As[r * 64 + ch * 8];
            }
#pragma unroll
            for (int ni = 0; ni < 4; ++ni) {
                int r = wn + ni * 16 + lane16;
                int ch = (ks * 4 + quad) ^ (r & 7);
                bf[ni] = *(const s16x8*)&Bs[r * 64 + ch * 8];
            }
#pragma unroll
            for (int mi = 0; mi < 4; ++mi)
#pragma unroll
                for (int ni = 0; ni < 4; ++ni)
                    acc[mi][ni] = __builtin_amdgcn_mfma_f32_16x16x32_bf16(af[mi], bf[ni], acc[mi][ni], 0, 0, 0);
        }
        __syncthreads();
    }
#pragma unroll
    for (int ni = 0; ni < 4; ++ni) {
        int col = n0 + wn + ni * 16 + lane16;
        float bv = BIAS ? bias[col] : 0.0f;
#pragma unroll
        for (int mi = 0; mi < 4; ++mi) {
#pragma unroll
            for (int r = 0; r < 4; ++r) {
                int rowg = m0 + wm + mi * 16 + quad * 4 + r;
                float v = acc[mi][ni][r] + bv;
                if (OUTBF16)
                    ((u16*)Cout)[(size_t)rowg * N + col] = f2bf(v);
                else
                    ((float*)Cout)[(size_t)rowg * N + col] = v;
            }
        }
    }
}

// ---------------- 256x256 8-wave double-buffered counted-vmcnt MFMA GEMM -------------
// Use ONLY when grid <= 256 blocks (single scheduling round). ~120us per full round.
template <bool BIAS, bool OUTBF16>
__global__ __launch_bounds__(512, 2) void gemm256_kernel(const u16* __restrict__ A,
                                                         const u16* __restrict__ Bt,
                                                         const float* __restrict__ bias,
                                                         void* __restrict__ Cout,
                                                         int M, int N, int K) {
    __shared__ __align__(16) u16 As[2 * 256 * 64];
    __shared__ __align__(16) u16 Bs[2 * 256 * 64];
    int t = threadIdx.x;
    int w = t >> 6, l = t & 63;
    int lane16 = l & 15, quad = l >> 4;
    int m0 = blockIdx.y * 256, n0 = blockIdx.x * 256;
    int wm2 = w >> 2, wn4 = w & 3;   // 2 x 4 wave grid

    f32x4 z = {0.f, 0.f, 0.f, 0.f};
    f32x4 acc[8][4];
#pragma unroll
    for (int i = 0; i < 8; ++i)
#pragma unroll
        for (int j = 0; j < 4; ++j) acc[i][j] = z;

    auto STAGE = [&](int p, int kt) {
        const u16* ak = A + kt * 64;
        const u16* bk = Bt + kt * 64;
#pragma unroll
        for (int j = 0; j < 4; ++j) {
            int idx = j * 512 + t;
            int row = idx >> 3;
            int cg = (idx & 7) ^ (row & 7);
            async_load16(ak + (size_t)(m0 + row) * K + cg * 8,
                         As + p * 16384 + j * 4096 + w * 512);
        }
#pragma unroll
        for (int j = 0; j < 4; ++j) {
            int idx = j * 512 + t;
            int row = idx >> 3;
            int cg = (idx & 7) ^ (row & 7);
            async_load16(bk + (size_t)(n0 + row) * K + cg * 8,
                         Bs + p * 16384 + j * 4096 + w * 512);
        }
    };

    auto COMPUTE = [&](int p) {
        const u16* Asp = As + p * 16384;
        const u16* Bsp = Bs + p * 16384;
#pragma unroll
        for (int mh = 0; mh < 2; ++mh) {
            s16x8 af[4][2];
#pragma unroll
            for (int mi = 0; mi < 4; ++mi) {
                int r = wm2 * 128 + mh * 64 + mi * 16 + lane16;
#pragma unroll
                for (int ks = 0; ks < 2; ++ks) {
                    int ch = (ks * 4 + quad) ^ (r & 7);
                    af[mi][ks] = *(const s16x8*)&Asp[r * 64 + ch * 8];
                }
            }
#pragma unroll
            for (int nh = 0; nh < 2; ++nh) {
                s16x8 bfr[2][2];
#pragma unroll
                for (int ni = 0; ni < 2; ++ni) {
                    int r = wn4 * 64 + nh * 32 + ni * 16 + lane16;
#pragma unroll
                    for (int ks = 0; ks < 2; ++ks) {
                        int ch = (ks * 4 + quad) ^ (r & 7);
                        bfr[ni][ks] = *(const s16x8*)&Bsp[r * 64 + ch * 8];
                    }
                }
                __builtin_amdgcn_s_setprio(1);
#pragma unroll
                for (int ks = 0; ks < 2; ++ks)
#pragma unroll
                    for (int mi = 0; mi < 4; ++mi)
#pragma unroll
                        for (int ni = 0; ni < 2; ++ni)
                            acc[mh * 4 + mi][nh * 2 + ni] = __builtin_amdgcn_mfma_f32_16x16x32_bf16(
                                af[mi][ks], bfr[ni][ks], acc[mh * 4 + mi][nh * 2 + ni], 0, 0, 0);
                __builtin_amdgcn_s_setprio(0);
            }
        }
    };

    int nk = K >> 6;
    STAGE(0, 0);
#pragma unroll 1
    for (int kt = 0; kt < nk; ++kt) {
        int p = kt & 1;
        if (kt + 1 < nk) {
            STAGE(p ^ 1, kt + 1);                              // next tile in flight
            asm volatile("s_waitcnt vmcnt(8)" ::: "memory");   // tile kt done; kt+1 stays in flight
        } else {
            asm volatile("s_waitcnt vmcnt(0)" ::: "memory");
        }
        __builtin_amdgcn_s_barrier();          // all waves' tile-kt loads landed
        __builtin_amdgcn_sched_barrier(0);     // no ds_read hoists above the barrier
        COMPUTE(p);
        asm volatile("s_waitcnt lgkmcnt(0)" ::: "memory");
        __builtin_amdgcn_s_barrier();          // all waves done reading buf p
    }

#pragma unroll
    for (int nj = 0; nj < 4; ++nj) {
        int col = n0 + wn4 * 64 + nj * 16 + lane16;
        float bv = BIAS ? bias[col] : 0.0f;
#pragma unroll
        for (int mj = 0; mj < 8; ++mj) {
#pragma unroll
            for (int r = 0; r < 4; ++r) {
                int rowg = m0 + wm2 * 128 + mj * 16 + quad * 4 + r;
                float v = acc[mj][nj][r] + bv;
                if (OUTBF16)
                    ((u16*)Cout)[(size_t)rowg * N + col] = f2bf(v);
                else
                    ((float*)Cout)[(size_t)rowg * N + col] = v;
            }
        }
    }
}

// ---------------- RoPE (Q,K; V handled by vtrans_kernel) ----------------
__global__ __launch_bounds__(256) void rope_kernel(const u16* __restrict__ qkv,
                                                   const int* __restrict__ positions,
                                                   u16* __restrict__ Q, u16* __restrict__ Kout) {
    int row = blockIdx.x;           // b*S + s
    int b = row >> 11, s = row & 2047;
    int t = threadIdx.x;
    int i = t & 63;
    int g = t >> 6;
    float pos = (float)positions[row];
    float freq = exp2f((float)(2 * i) * (-13.287712379549449f / 128.0f));
    float ang = pos * freq;
    float sn, cs;
    sincosf(ang, &sn, &cs);
    const u16* qrow = qkv + (size_t)row * QKV_N;
#pragma unroll
    for (int hh = 0; hh < 7; ++hh) {
        int h = g * 7 + hh;
        float x1 = bf2f(qrow[h * HD + i]);
        float x2 = bf2f(qrow[h * HD + 64 + i]);
        u16* qo = Q + ((size_t)(b * NH + h) * S_LEN + s) * HD;
        qo[i]      = f2bf((x1 * cs - x2 * sn) * RSCALE);
        qo[64 + i] = f2bf((x2 * cs + x1 * sn) * RSCALE);
    }
    {
        float x1 = bf2f(qrow[QSZ + g * HD + i]);
        float x2 = bf2f(qrow[QSZ + g * HD + 64 + i]);
        u16* ko = Kout + ((size_t)(b * NKV + g) * S_LEN + s) * HD;
        ko[i]      = f2bf(x1 * cs - x2 * sn);
        ko[64 + i] = f2bf(x2 * cs + x1 * sn);
    }
}

// ---------------- V transpose: qkv[:, QSZ+KVSZ:] -> Vt[b][c][s] (u16, LDS-tiled) ----------------
__global__ __launch_bounds__(256) void vtrans_kernel(const u16* __restrict__ qkv,
                                                     u16* __restrict__ Vt) {
    __shared__ u16 T[64 * 72];
    int t = threadIdx.x;
    int c0 = blockIdx.x * 64, s0 = blockIdx.y * 64, b = blockIdx.z;
    const u16* src = qkv + (size_t)b * 2048 * QKV_N + QSZ + KVSZ + c0;
#pragma unroll
    for (int i = 0; i < 2; ++i) {
        int idx = i * 256 + t;
        int sr = idx >> 3, ch = idx & 7;
        u16x8 v = *(const u16x8*)&src[(size_t)(s0 + sr) * QKV_N + ch * 8];
#pragma unroll
        for (int j = 0; j < 8; ++j) T[(ch * 8 + j) * 72 + sr] = v[j];
    }
    __syncthreads();
    u16* dst = Vt + (size_t)b * 512 * 2048;
#pragma unroll
    for (int i = 0; i < 2; ++i) {
        int idx = i * 256 + t;
        int cr = idx >> 3, ch = idx & 7;
        *(u16x8*)&dst[(size_t)(c0 + cr) * 2048 + s0 + ch * 8] = *(const u16x8*)&T[cr * 72 + ch * 8];
    }
}

// ---------------- flash attention (causal, GQA-fused) ----------------
// Round-4 base (known-good) + two softmax changes:
//  - T13 defer-max: skip O/l rescale when __all(mx <= m+8); P bounded by e^8 (bf16-safe).
//  - MFMA row-sum: l accumulated via mfma(P, ones) into acc_l (D row = quad*4+r matches
//    sa/oacc row layout) -> removes the 16-shfl rs reduction from the critical path.
__global__ __launch_bounds__(512, 2) void attn_kernel(const u16* __restrict__ Q,
                                                      const u16* __restrict__ K,
                                                      const u16* __restrict__ Vt,
                                                      u16* __restrict__ O) {
    __shared__ __align__(16) u16 Ks[64 * 128];
    __shared__ __align__(16) u16 Vs[128 * 64];
    __shared__ __align__(16) u16 Ps[7 * 16 * 72];
    int p = blockIdx.x;             // 0..31  (q-tile pair)
    int bh = blockIdx.y;            // b*4 + hk
    int b = bh >> 2, hk = bh & 3;
    int t = threadIdx.x, w = t >> 6, l = t & 63;
    int lane16 = l & 15, quad = l >> 4;
    const u16* Kb = K + (size_t)(b * NKV + hk) * S_LEN * HD;
    const u16* Vb = Vt + (size_t)(b * NKV + hk) * HD * S_LEN;
    int wc = (w < 7) ? w : 6;       // clamp so wave 7's pointer math stays in-bounds
    int h = hk * 7 + wc;
    const u16* Qb = Q + (size_t)(b * NH + h) * S_LEN * HD;
    u16* Pw = Ps + wc * (16 * 72);

    const s16x8 onesv = {0x3F80, 0x3F80, 0x3F80, 0x3F80, 0x3F80, 0x3F80, 0x3F80, 0x3F80};

    u16x8 kr[2], vr_[2];
    auto stageR = [&](int kt) {
#pragma unroll
        for (int j = 0; j < 2; ++j) {
            int idx = j * 512 + t;
            kr[j] = *(const u16x8*)&Kb[(size_t)(kt * 64 + (idx >> 4)) * HD + (idx & 15) * 8];
        }
#pragma unroll
        for (int j = 0; j < 2; ++j) {
            int idx = j * 512 + t;
            vr_[j] = *(const u16x8*)&Vb[(size_t)(idx >> 3) * S_LEN + kt * 64 + (idx & 7) * 8];
        }
    };
    auto dsw = [&]() {
#pragma unroll
        for (int j = 0; j < 2; ++j) {
            int idx = j * 512 + t;
            int row = idx >> 4, c = idx & 15;
            *(u16x8*)&Ks[row * 128 + (c ^ (row & 15)) * 8] = kr[j];
        }
#pragma unroll
        for (int j = 0; j < 2; ++j) {
            int idx = j * 512 + t;
            int row = idx >> 3, c = idx & 7;
            *(u16x8*)&Vs[row * 64 + (c ^ (row & 7)) * 8] = vr_[j];
        }
    };

    f32x4 z = {0.f, 0.f, 0.f, 0.f};

#pragma unroll 1
    for (int phase = 0; phase < 2; ++phase) {
        int q0 = (phase == 0) ? p * 32 : (63 - p) * 32;
        int nkt = (q0 >> 6) + 1;

        s16x8 qf[2][4];
        if (w < 7) {
#pragma unroll
            for (int st = 0; st < 2; ++st) {
                int qrow = q0 + st * 16 + lane16;
#pragma unroll
                for (int kd = 0; kd < 4; ++kd)
                    qf[st][kd] = *(const s16x8*)(Qb + (size_t)qrow * HD + kd * 32 + quad * 8);
            }
        }
        f32x4 oacc[2][8];
        f32x4 acc_l[2];
        float m_r[2][4];
#pragma unroll
        for (int st = 0; st < 2; ++st) {
#pragma unroll
            for (int i = 0; i < 8; ++i) oacc[st][i] = z;
            acc_l[st] = z;
#pragma unroll
            for (int r = 0; r < 4; ++r) m_r[st][r] = -3.0e38f;
        }

        stageR(0);
#pragma unroll 1
        for (int kt = 0; kt < nkt; ++kt) {
            __syncthreads();                 // all waves done reading previous tile
            dsw();                           // LDS <- regs (tile kt)
            __syncthreads();
            if (kt + 1 < nkt) stageR(kt + 1);  // issue next tile's global loads now
            if (w < 7) {
#pragma unroll
                for (int st = 0; st < 2; ++st) {
                    f32x4 sa[4];
                    sa[0] = z; sa[1] = z; sa[2] = z; sa[3] = z;
#pragma unroll
                    for (int kd = 0; kd < 4; ++kd) {
#pragma unroll
                        for (int ni = 0; ni < 4; ++ni) {
                            int srow = ni * 16 + lane16;
                            int ch = (kd * 4 + quad) ^ lane16;
                            s16x8 kf = *(const s16x8*)&Ks[srow * 128 + ch * 8];
                            sa[ni] = __builtin_amdgcn_mfma_f32_16x16x32_bf16(qf[st][kd], kf, sa[ni], 0, 0, 0);
                        }
                    }
                    if (kt == nkt - 1) {
#pragma unroll
                        for (int ni = 0; ni < 4; ++ni)
#pragma unroll
                            for (int r = 0; r < 4; ++r) {
                                int colg = kt * 64 + ni * 16 + lane16;
                                int rowg = q0 + st * 16 + quad * 4 + r;
                                if (colg > rowg) sa[ni][r] = -3.0e38f;
                            }
                    }
                    float mx[4];
#pragma unroll
                    for (int r = 0; r < 4; ++r) {
                        mx[r] = fmaxf(fmaxf(sa[0][r], sa[1][r]), fmaxf(sa[2][r], sa[3][r]));
                        mx[r] = fmaxf(mx[r], __shfl_xor(mx[r], 1));
                        mx[r] = fmaxf(mx[r], __shfl_xor(mx[r], 2));
                        mx[r] = fmaxf(mx[r], __shfl_xor(mx[r], 4));
                        mx[r] = fmaxf(mx[r], __shfl_xor(mx[r], 8));
                    }
                    // T13 defer-max: only rescale when some row's max grew by > 8
                    int ok = (mx[0] <= m_r[st][0] + 8.0f) && (mx[1] <= m_r[st][1] + 8.0f) &&
                             (mx[2] <= m_r[st][2] + 8.0f) && (mx[3] <= m_r[st][3] + 8.0f);
                    if (!__all(ok)) {
                        float al[4];
#pragma unroll
                        for (int r = 0; r < 4; ++r) {
                            float mn = fmaxf(m_r[st][r], mx[r]);
                            al[r] = __expf(m_r[st][r] - mn);
                            m_r[st][r] = mn;
                        }
#pragma unroll
                        for (int i = 0; i < 8; ++i)
#pragma unroll
                            for (int r = 0; r < 4; ++r) oacc[st][i][r] *= al[r];
#pragma unroll
                        for (int r = 0; r < 4; ++r) acc_l[st][r] *= al[r];
                    }
                    float pp[4][4];
#pragma unroll
                    for (int ni = 0; ni < 4; ++ni)
#pragma unroll
                        for (int r = 0; r < 4; ++r)
                            pp[ni][r] = __expf(sa[ni][r] - m_r[st][r]);
                    // P: C-layout -> A-layout via per-wave LDS region
#pragma unroll
                    for (int ni = 0; ni < 4; ++ni)
#pragma unroll
                        for (int r = 0; r < 4; ++r)
                            Pw[(quad * 4 + r) * 72 + ni * 16 + lane16] = f2bf(pp[ni][r]);
#pragma unroll
                    for (int ks = 0; ks < 2; ++ks) {
                        s16x8 pf = *(const s16x8*)&Pw[lane16 * 72 + ks * 32 + quad * 8];
                        // l row-sum via MFMA (B = ones): D[row][*] = sum_k P[row][k]
                        acc_l[st] = __builtin_amdgcn_mfma_f32_16x16x32_bf16(pf, onesv, acc_l[st], 0, 0, 0);
#pragma unroll
                        for (int ni2 = 0; ni2 < 8; ++ni2) {
                            int vr = ni2 * 16 + lane16;
                            int ch = (ks * 4 + quad) ^ (vr & 7);
                            s16x8 vf = *(const s16x8*)&Vs[vr * 64 + ch * 8];
                            oacc[st][ni2] = __builtin_amdgcn_mfma_f32_16x16x32_bf16(pf, vf, oacc[st][ni2], 0, 0, 0);
                        }
                    }
                }
            }
        }
        // epilogue for this q-tile
        if (w < 7) {
#pragma unroll
            for (int st = 0; st < 2; ++st) {
                float inv[4];
#pragma unroll
                for (int r = 0; r < 4; ++r) inv[r] = 1.0f / acc_l[st][r];
#pragma unroll
                for (int ni2 = 0; ni2 < 8; ++ni2)
#pragma unroll
                    for (int r = 0; r < 4; ++r) {
                        int rowg = q0 + st * 16 + quad * 4 + r;
                        int colg = h * HD + ni2 * 16 + lane16;
                        O[((size_t)b * S_LEN + rowg) * QSZ + colg] = f2bf(oacc[st][ni2][r] * inv[r]);
                    }
            }
        }
    }
}

extern "C" void kernel_launch(void* const* d_in, const int* in_sizes, int n_in,
                              void* d_out, int out_size, void* d_ws, size_t ws_size,
                              hipStream_t stream) {
    const int* positions = (const int*)d_in[0];
    const float* hs = (const float*)d_in[1];
    const float* Wqkv = (const float*)d_in[2];
    const float* bqkv = (const float*)d_in[3];
    const float* Wo = (const float*)d_in[4];
    float* out = (float*)d_out;
    char* ws = (char*)d_ws;

    u16* hsb   = (u16*)(ws + 0);          // later reused as Q
    u16* Wqkvt = (u16*)(ws + 29360128);
    u16* Wot   = (u16*)(ws + 62390272);
    u16* qkv   = (u16*)(ws + 88080384);   // later reused as attn out
    u16* Kbuf  = (u16*)(ws + 125829120);
    u16* Vtb   = (u16*)(ws + 130023424);
    u16* Qbuf  = hsb;
    u16* attn  = qkv;

    hipLaunchKernelGGL(cvt_bf16_kernel, dim3(14336), dim3(256), 0, stream, hs, hsb, 3670016);
    hipLaunchKernelGGL(transpose_cvt_kernel, dim3(144, 112), dim3(256), 0, stream, Wqkv, Wqkvt, 3584, 4608);
    hipLaunchKernelGGL(transpose_cvt_kernel, dim3(112, 112), dim3(256), 0, stream, Wo, Wot, 3584, 3584);
    // QKV split to kill the 288-block tail: cols [0,4096) = 16x16 = EXACTLY 256
    // gemm256 blocks (one full scheduling round), cols [4096,4608) = 4x32 = 128
    // gemm-128^2 blocks (partial round, ~50us). Offsets: Bt rows 4096.., bias+4096,
    // Cout+4096 elements with stride N=4608.
    hipLaunchKernelGGL((gemm256_kernel<true, true>), dim3(16, 16), dim3(512), 0, stream,
                       hsb, Wqkvt, bqkv, (void*)qkv, 4096, 4608, 3584);
    hipLaunchKernelGGL((gemm_kernel<true, true>), dim3(4, 32), dim3(256), 0, stream,
                       hsb, Wqkvt + (size_t)4096 * 3584, bqkv + 4096, (void*)(qkv + 4096),
                       4096, 4608, 3584);
    hipLaunchKernelGGL(rope_kernel, dim3(4096), dim3(256), 0, stream, qkv, positions, Qbuf, Kbuf);
    hipLaunchKernelGGL(vtrans_kernel, dim3(8, 32, 2), dim3(256), 0, stream, qkv, Vtb);
    hipLaunchKernelGGL(attn_kernel, dim3(32, 8), dim3(512), 0, stream, Qbuf, Kbuf, Vtb, attn);
    // Out-proj: 224 tiles < 256 CUs -> single round.
    hipLaunchKernelGGL((gemm256_kernel<false, false>), dim3(14, 16), dim3(512), 0, stream,
                       attn, Wot, (const float*)nullptr, (void*)out, 4096, 3584, 3584);
}